// Round 1
// baseline (1159.365 us; speedup 1.0000x reference)
//
#include <hip/hip_runtime.h>
#include <stdint.h>

#define BATCH 32
#define NPTS  262144
#define KSEL  1024
#define NBIN  65536
#define CAP   4096

// ws layout
#define HIST_BYTES   ((size_t)BATCH * NBIN * 4)          // 8 MiB
#define THRESH_OFF   (HIST_BYTES)                        // 128 B
#define CNT_OFF      (HIST_BYTES + 128)                  // 128 B
#define CAND_OFF     (HIST_BYTES + 256)                  // 1 MiB
#define ZERO_BYTES   (HIST_BYTES + 256)

__device__ __forceinline__ uint32_t dist_bits(float x, float y, float z,
                                              float px, float py, float pz) {
#pragma clang fp contract(off)
    float dx = x - px;
    float dy = y - py;
    float dz = z - pz;
    float s = ((dx * dx) + (dy * dy)) + (dz * dz);
    return __float_as_uint(sqrtf(s));
}

// Pass 1: distance + histogram of top-16 float bits.
__global__ void dist_hist_kernel(const float* __restrict__ pc,
                                 const float* __restrict__ P1,
                                 uint32_t* __restrict__ hist) {
    int gid = blockIdx.x * blockDim.x + threadIdx.x;   // BATCH * NPTS/4 threads
    int b = gid >> 16;                                  // NPTS/4 == 65536
    int n = (gid & 65535) << 2;
    const float* base = pc + (size_t)b * 3 * NPTS;
    float4 x = *(const float4*)(base + n);
    float4 y = *(const float4*)(base + NPTS + n);
    float4 z = *(const float4*)(base + 2 * NPTS + n);
    float px = P1[b * 3 + 0];
    float py = P1[b * 3 + 1];
    float pz = P1[b * 3 + 2];
    uint32_t* h = hist + (size_t)b * NBIN;
    atomicAdd(&h[dist_bits(x.x, y.x, z.x, px, py, pz) >> 16], 1u);
    atomicAdd(&h[dist_bits(x.y, y.y, z.y, px, py, pz) >> 16], 1u);
    atomicAdd(&h[dist_bits(x.z, y.z, z.z, px, py, pz) >> 16], 1u);
    atomicAdd(&h[dist_bits(x.w, y.w, z.w, px, py, pz) >> 16], 1u);
}

// Pass 2: find per-batch threshold bin T (the bin containing the K-th smallest).
__global__ void thresh_kernel(const uint32_t* __restrict__ hist,
                              uint32_t* __restrict__ thresh) {
    int b = blockIdx.x;
    const uint32_t* h = hist + (size_t)b * NBIN;
    __shared__ uint32_t csum[256];
    int tid = threadIdx.x;  // 256 threads, each sums a 256-bin chunk
    uint32_t s = 0;
    for (int i = 0; i < 256; ++i) s += h[tid * 256 + i];
    csum[tid] = s;
    __syncthreads();
    if (tid == 0) {
        uint32_t acc = 0;
        int chunk = 0;
        for (; chunk < 256; ++chunk) {
            if (acc + csum[chunk] >= (uint32_t)KSEL) break;
            acc += csum[chunk];
        }
        uint32_t t = chunk * 256;
        for (int i = 0; i < 256; ++i) {
            uint32_t c = h[chunk * 256 + i];
            if (acc + c >= (uint32_t)KSEL) { t = chunk * 256 + i; break; }
            acc += c;
        }
        thresh[b] = t;
    }
}

// Pass 3: compact candidate keys (distbits<<32 | index) for bins <= T.
__global__ void compact_kernel(const float* __restrict__ pc,
                               const float* __restrict__ P1,
                               const uint32_t* __restrict__ thresh,
                               uint32_t* __restrict__ cnt,
                               uint64_t* __restrict__ cand) {
    int gid = blockIdx.x * blockDim.x + threadIdx.x;
    int b = gid >> 16;
    int n = (gid & 65535) << 2;
    const float* base = pc + (size_t)b * 3 * NPTS;
    float4 x = *(const float4*)(base + n);
    float4 y = *(const float4*)(base + NPTS + n);
    float4 z = *(const float4*)(base + 2 * NPTS + n);
    float px = P1[b * 3 + 0];
    float py = P1[b * 3 + 1];
    float pz = P1[b * 3 + 2];
    uint32_t T = thresh[b];
    uint32_t bits[4];
    bits[0] = dist_bits(x.x, y.x, z.x, px, py, pz);
    bits[1] = dist_bits(x.y, y.y, z.y, px, py, pz);
    bits[2] = dist_bits(x.z, y.z, z.z, px, py, pz);
    bits[3] = dist_bits(x.w, y.w, z.w, px, py, pz);
#pragma unroll
    for (int i = 0; i < 4; ++i) {
        if ((bits[i] >> 16) <= T) {
            uint32_t pos = atomicAdd(&cnt[b], 1u);
            if (pos < CAP)
                cand[(size_t)b * CAP + pos] =
                    ((uint64_t)bits[i] << 32) | (uint32_t)(n + i);
        }
    }
}

// Pass 4: per-batch bitonic sort of candidates in LDS, write K results.
__global__ __launch_bounds__(1024) void sort_out_kernel(
        const float* __restrict__ pc,
        const uint32_t* __restrict__ cnt,
        const uint64_t* __restrict__ cand,
        float* __restrict__ out) {
    __shared__ uint64_t keys[CAP];
    int b = blockIdx.x;
    int tid = threadIdx.x;
    uint32_t m = cnt[b];
    if (m > CAP) m = CAP;
    for (int i = tid; i < CAP; i += 1024)
        keys[i] = (i < (int)m) ? cand[(size_t)b * CAP + i] : 0xFFFFFFFFFFFFFFFFull;
    __syncthreads();
    for (int k = 2; k <= CAP; k <<= 1) {
        for (int j = k >> 1; j > 0; j >>= 1) {
            for (int i = tid; i < CAP; i += 1024) {
                int ixj = i ^ j;
                if (ixj > i) {
                    uint64_t a = keys[i];
                    uint64_t c = keys[ixj];
                    bool up = ((i & k) == 0);
                    if ((a > c) == up) { keys[i] = c; keys[ixj] = a; }
                }
            }
            __syncthreads();
        }
    }
    float* out_near = out;                        // (B,3,K)
    float* out_idx  = out + (size_t)BATCH * 3 * KSEL;  // (B,K)
    const float* base = pc + (size_t)b * 3 * NPTS;
    for (int kk = tid; kk < KSEL; kk += 1024) {
        uint64_t key = keys[kk];
        uint32_t idx = (uint32_t)key;
        out_idx[(size_t)b * KSEL + kk] = (float)idx;
        out_near[((size_t)b * 3 + 0) * KSEL + kk] = base[idx];
        out_near[((size_t)b * 3 + 1) * KSEL + kk] = base[NPTS + idx];
        out_near[((size_t)b * 3 + 2) * KSEL + kk] = base[2 * NPTS + idx];
    }
}

extern "C" void kernel_launch(void* const* d_in, const int* in_sizes, int n_in,
                              void* d_out, int out_size, void* d_ws, size_t ws_size,
                              hipStream_t stream) {
    const float* pc = (const float*)d_in[0];
    const float* P1 = (const float*)d_in[1];
    float* out = (float*)d_out;

    uint32_t* hist   = (uint32_t*)d_ws;
    uint32_t* thresh = (uint32_t*)((char*)d_ws + THRESH_OFF);
    uint32_t* cnt    = (uint32_t*)((char*)d_ws + CNT_OFF);
    uint64_t* cand   = (uint64_t*)((char*)d_ws + CAND_OFF);

    hipMemsetAsync(d_ws, 0, ZERO_BYTES, stream);

    int threads = 256;
    int blocks = (BATCH * (NPTS / 4)) / threads;  // 8192
    dist_hist_kernel<<<blocks, threads, 0, stream>>>(pc, P1, hist);
    thresh_kernel<<<BATCH, 256, 0, stream>>>(hist, thresh);
    compact_kernel<<<blocks, threads, 0, stream>>>(pc, P1, thresh, cnt, cand);
    sort_out_kernel<<<BATCH, 1024, 0, stream>>>(pc, cnt, cand, out);
}

// Round 2
// 254.612 us; speedup vs baseline: 4.5535x; 4.5535x over previous
//
#include <hip/hip_runtime.h>
#include <stdint.h>

#define BATCH 32
#define NPTS  262144
#define KSEL  1024
#define NBIN  8192          // 13-bit bins: sign+exp+4 mantissa
#define BSHIFT 19           // 32-13
#define CAP   4096

#define HBLK  512           // histogram/compact blocks
#define BPB   16            // blocks per batch (HBLK/BATCH)
#define PPB   16384         // points per block (NPTS/BPB)

// ws layout
#define HIST_BYTES   ((size_t)BATCH * NBIN * 4)          // 1 MiB
#define THRESH_OFF   (HIST_BYTES)                        // 128 B
#define CNT_OFF      (HIST_BYTES + 128)                  // 128 B
#define CAND_OFF     (HIST_BYTES + 256)                  // 1 MiB
#define ZERO_BYTES   (HIST_BYTES + 256)

__device__ __forceinline__ uint32_t dist_bits(float x, float y, float z,
                                              float px, float py, float pz) {
#pragma clang fp contract(off)
    float dx = x - px;
    float dy = y - py;
    float dz = z - pz;
    float s = ((dx * dx) + (dy * dy)) + (dz * dz);
    return __float_as_uint(sqrtf(s));
}

// Pass 1: distance + LDS-privatized histogram of top-13 float bits.
__global__ __launch_bounds__(256) void hist_kernel(const float* __restrict__ pc,
                                                   const float* __restrict__ P1,
                                                   uint32_t* __restrict__ hist) {
    __shared__ uint32_t lh[NBIN];
    for (int i = threadIdx.x; i < NBIN; i += 256) lh[i] = 0;
    __syncthreads();

    const int b = blockIdx.x >> 4;          // BPB==16 blocks per batch
    const int slice = blockIdx.x & 15;
    const float* base = pc + (size_t)b * 3 * NPTS;
    const int n0 = slice * PPB;
    const float px = P1[b * 3 + 0];
    const float py = P1[b * 3 + 1];
    const float pz = P1[b * 3 + 2];

#pragma unroll 4
    for (int it = 0; it < PPB / (256 * 4); ++it) {     // 16 iterations
        int n = n0 + ((it * 256 + threadIdx.x) << 2);
        float4 x = *(const float4*)(base + n);
        float4 y = *(const float4*)(base + NPTS + n);
        float4 z = *(const float4*)(base + 2 * NPTS + n);
        atomicAdd(&lh[dist_bits(x.x, y.x, z.x, px, py, pz) >> BSHIFT], 1u);
        atomicAdd(&lh[dist_bits(x.y, y.y, z.y, px, py, pz) >> BSHIFT], 1u);
        atomicAdd(&lh[dist_bits(x.z, y.z, z.z, px, py, pz) >> BSHIFT], 1u);
        atomicAdd(&lh[dist_bits(x.w, y.w, z.w, px, py, pz) >> BSHIFT], 1u);
    }
    __syncthreads();

    uint32_t* h = hist + (size_t)b * NBIN;
    for (int i = threadIdx.x; i < NBIN; i += 256) {
        uint32_t c = lh[i];
        if (c) atomicAdd(&h[i], c);
    }
}

// Pass 2: per-batch threshold bin T (bin containing the K-th smallest).
__global__ void thresh_kernel(const uint32_t* __restrict__ hist,
                              uint32_t* __restrict__ thresh) {
    int b = blockIdx.x;
    const uint32_t* h = hist + (size_t)b * NBIN;
    __shared__ uint32_t csum[256];
    int tid = threadIdx.x;                   // 256 threads × 32 bins each
    uint32_t s = 0;
    for (int i = 0; i < 32; ++i) s += h[tid * 32 + i];
    csum[tid] = s;
    __syncthreads();
    if (tid == 0) {
        uint32_t acc = 0;
        int chunk = 0;
        for (; chunk < 256; ++chunk) {
            if (acc + csum[chunk] >= (uint32_t)KSEL) break;
            acc += csum[chunk];
        }
        uint32_t t = chunk * 32;
        for (int i = 0; i < 32; ++i) {
            uint32_t c = h[chunk * 32 + i];
            if (acc + c >= (uint32_t)KSEL) { t = chunk * 32 + i; break; }
            acc += c;
        }
        thresh[b] = t;
    }
}

// Pass 3: compact candidate keys (distbits<<32 | index) for bins <= T.
__global__ __launch_bounds__(256) void compact_kernel(
        const float* __restrict__ pc,
        const float* __restrict__ P1,
        const uint32_t* __restrict__ thresh,
        uint32_t* __restrict__ cnt,
        uint64_t* __restrict__ cand) {
    const int b = blockIdx.x >> 4;
    const int slice = blockIdx.x & 15;
    const float* base = pc + (size_t)b * 3 * NPTS;
    const int n0 = slice * PPB;
    const float px = P1[b * 3 + 0];
    const float py = P1[b * 3 + 1];
    const float pz = P1[b * 3 + 2];
    const uint32_t T = thresh[b];

    for (int it = 0; it < PPB / (256 * 4); ++it) {
        int n = n0 + ((it * 256 + threadIdx.x) << 2);
        float4 x = *(const float4*)(base + n);
        float4 y = *(const float4*)(base + NPTS + n);
        float4 z = *(const float4*)(base + 2 * NPTS + n);
        uint32_t bits[4];
        bits[0] = dist_bits(x.x, y.x, z.x, px, py, pz);
        bits[1] = dist_bits(x.y, y.y, z.y, px, py, pz);
        bits[2] = dist_bits(x.z, y.z, z.z, px, py, pz);
        bits[3] = dist_bits(x.w, y.w, z.w, px, py, pz);
#pragma unroll
        for (int i = 0; i < 4; ++i) {
            if ((bits[i] >> BSHIFT) <= T) {
                uint32_t pos = atomicAdd(&cnt[b], 1u);
                if (pos < CAP)
                    cand[(size_t)b * CAP + pos] =
                        ((uint64_t)bits[i] << 32) | (uint32_t)(n + i);
            }
        }
    }
}

// Pass 4: per-batch bitonic sort (next-pow2 of candidate count) + output.
__global__ __launch_bounds__(1024) void sort_out_kernel(
        const float* __restrict__ pc,
        const uint32_t* __restrict__ cnt,
        const uint64_t* __restrict__ cand,
        float* __restrict__ out) {
    __shared__ uint64_t keys[CAP];
    int b = blockIdx.x;
    int tid = threadIdx.x;
    uint32_t m = cnt[b];
    if (m > CAP) m = CAP;
    int S = KSEL;                       // m >= KSEL always
    while (S < (int)m) S <<= 1;         // S in [1024, 4096]
    for (int i = tid; i < S; i += 1024)
        keys[i] = (i < (int)m) ? cand[(size_t)b * CAP + i] : 0xFFFFFFFFFFFFFFFFull;
    __syncthreads();
    for (int k = 2; k <= S; k <<= 1) {
        for (int j = k >> 1; j > 0; j >>= 1) {
            for (int i = tid; i < S; i += 1024) {
                int ixj = i ^ j;
                if (ixj > i) {
                    uint64_t a = keys[i];
                    uint64_t c = keys[ixj];
                    bool up = ((i & k) == 0);
                    if ((a > c) == up) { keys[i] = c; keys[ixj] = a; }
                }
            }
            __syncthreads();
        }
    }
    float* out_near = out;                             // (B,3,K)
    float* out_idx  = out + (size_t)BATCH * 3 * KSEL;  // (B,K)
    const float* base = pc + (size_t)b * 3 * NPTS;
    for (int kk = tid; kk < KSEL; kk += 1024) {
        uint64_t key = keys[kk];
        uint32_t idx = (uint32_t)key;
        out_idx[(size_t)b * KSEL + kk] = (float)idx;
        out_near[((size_t)b * 3 + 0) * KSEL + kk] = base[idx];
        out_near[((size_t)b * 3 + 1) * KSEL + kk] = base[NPTS + idx];
        out_near[((size_t)b * 3 + 2) * KSEL + kk] = base[2 * NPTS + idx];
    }
}

extern "C" void kernel_launch(void* const* d_in, const int* in_sizes, int n_in,
                              void* d_out, int out_size, void* d_ws, size_t ws_size,
                              hipStream_t stream) {
    const float* pc = (const float*)d_in[0];
    const float* P1 = (const float*)d_in[1];
    float* out = (float*)d_out;

    uint32_t* hist   = (uint32_t*)d_ws;
    uint32_t* thresh = (uint32_t*)((char*)d_ws + THRESH_OFF);
    uint32_t* cnt    = (uint32_t*)((char*)d_ws + CNT_OFF);
    uint64_t* cand   = (uint64_t*)((char*)d_ws + CAND_OFF);

    hipMemsetAsync(d_ws, 0, ZERO_BYTES, stream);

    hist_kernel<<<HBLK, 256, 0, stream>>>(pc, P1, hist);
    thresh_kernel<<<BATCH, 256, 0, stream>>>(hist, thresh);
    compact_kernel<<<HBLK, 256, 0, stream>>>(pc, P1, thresh, cnt, cand);
    sort_out_kernel<<<BATCH, 1024, 0, stream>>>(pc, cnt, cand, out);
}

// Round 3
// 82.838 us; speedup vs baseline: 13.9955x; 3.0736x over previous
//
#include <hip/hip_runtime.h>
#include <stdint.h>

#define BATCH 32
#define NPTS  262144
#define KSEL  1024
#define NBIN  8192          // 13-bit bins: sign+exp+4 mantissa
#define BSHIFT 19           // 32-13
#define CAP   4096
#define CNT_STRIDE 32       // pad per-batch counters to 128 B

#define HBLK  512           // histogram blocks (16 per batch)
#define PPB_H 16384         // points per hist block

#define CBLK  2048          // compact blocks (64 per batch)
#define PPB_C 4096          // points per compact block
#define LCAP  1024          // per-block LDS candidate buffer

// ws layout
#define HIST_BYTES   ((size_t)BATCH * NBIN * 4)          // 1 MiB
#define THRESH_OFF   (HIST_BYTES)                        // 128 B
#define CNT_OFF      (HIST_BYTES + 128)                  // 32*128 B
#define CAND_OFF     (HIST_BYTES + 128 + BATCH * CNT_STRIDE * 4)
#define ZERO_BYTES   (CAND_OFF)

__device__ __forceinline__ uint32_t dist_bits(float x, float y, float z,
                                              float px, float py, float pz) {
#pragma clang fp contract(off)
    float dx = x - px;
    float dy = y - py;
    float dz = z - pz;
    float s = ((dx * dx) + (dy * dy)) + (dz * dz);
    return __float_as_uint(sqrtf(s));
}

// Pass 1: distance + LDS-privatized histogram of top-13 float bits.
__global__ __launch_bounds__(256) void hist_kernel(const float* __restrict__ pc,
                                                   const float* __restrict__ P1,
                                                   uint32_t* __restrict__ hist) {
    __shared__ uint32_t lh[NBIN];
    for (int i = threadIdx.x; i < NBIN; i += 256) lh[i] = 0;
    __syncthreads();

    const int b = blockIdx.x >> 4;          // 16 blocks per batch
    const int slice = blockIdx.x & 15;
    const float* base = pc + (size_t)b * 3 * NPTS;
    const int n0 = slice * PPB_H;
    const float px = P1[b * 3 + 0];
    const float py = P1[b * 3 + 1];
    const float pz = P1[b * 3 + 2];

#pragma unroll 4
    for (int it = 0; it < PPB_H / (256 * 4); ++it) {     // 16 iterations
        int n = n0 + ((it * 256 + threadIdx.x) << 2);
        float4 x = *(const float4*)(base + n);
        float4 y = *(const float4*)(base + NPTS + n);
        float4 z = *(const float4*)(base + 2 * NPTS + n);
        atomicAdd(&lh[dist_bits(x.x, y.x, z.x, px, py, pz) >> BSHIFT], 1u);
        atomicAdd(&lh[dist_bits(x.y, y.y, z.y, px, py, pz) >> BSHIFT], 1u);
        atomicAdd(&lh[dist_bits(x.z, y.z, z.z, px, py, pz) >> BSHIFT], 1u);
        atomicAdd(&lh[dist_bits(x.w, y.w, z.w, px, py, pz) >> BSHIFT], 1u);
    }
    __syncthreads();

    uint32_t* h = hist + (size_t)b * NBIN;
    for (int i = threadIdx.x; i < NBIN; i += 256) {
        uint32_t c = lh[i];
        if (c) atomicAdd(&h[i], c);
    }
}

// Pass 2: per-batch threshold bin T (bin containing the K-th smallest).
__global__ void thresh_kernel(const uint32_t* __restrict__ hist,
                              uint32_t* __restrict__ thresh) {
    int b = blockIdx.x;
    const uint32_t* h = hist + (size_t)b * NBIN;
    __shared__ uint32_t csum[256];
    int tid = threadIdx.x;                   // 256 threads × 32 bins each
    uint32_t s = 0;
    for (int i = 0; i < 32; ++i) s += h[tid * 32 + i];
    csum[tid] = s;
    __syncthreads();
    if (tid == 0) {
        uint32_t acc = 0;
        int chunk = 0;
        for (; chunk < 256; ++chunk) {
            if (acc + csum[chunk] >= (uint32_t)KSEL) break;
            acc += csum[chunk];
        }
        uint32_t t = chunk * 32;
        for (int i = 0; i < 32; ++i) {
            uint32_t c = h[chunk * 32 + i];
            if (acc + c >= (uint32_t)KSEL) { t = chunk * 32 + i; break; }
            acc += c;
        }
        thresh[b] = t;
    }
}

// Pass 3: compact candidates via LDS staging + one chunk-reservation atomic/block.
__global__ __launch_bounds__(256) void compact_kernel(
        const float* __restrict__ pc,
        const float* __restrict__ P1,
        const uint32_t* __restrict__ thresh,
        uint32_t* __restrict__ cnt,
        uint64_t* __restrict__ cand) {
    __shared__ uint64_t lbuf[LCAP];
    __shared__ uint32_t lcnt, lbase;
    if (threadIdx.x == 0) lcnt = 0;
    __syncthreads();

    const int b = blockIdx.x >> 6;          // 64 blocks per batch
    const int slice = blockIdx.x & 63;
    const float* base = pc + (size_t)b * 3 * NPTS;
    const int n0 = slice * PPB_C;
    const float px = P1[b * 3 + 0];
    const float py = P1[b * 3 + 1];
    const float pz = P1[b * 3 + 2];
    const uint32_t T = thresh[b];
    uint32_t* gcnt = &cnt[b * CNT_STRIDE];

#pragma unroll
    for (int it = 0; it < PPB_C / (256 * 4); ++it) {    // 4 iterations
        int n = n0 + ((it * 256 + threadIdx.x) << 2);
        float4 x = *(const float4*)(base + n);
        float4 y = *(const float4*)(base + NPTS + n);
        float4 z = *(const float4*)(base + 2 * NPTS + n);
        uint32_t bits[4];
        bits[0] = dist_bits(x.x, y.x, z.x, px, py, pz);
        bits[1] = dist_bits(x.y, y.y, z.y, px, py, pz);
        bits[2] = dist_bits(x.z, y.z, z.z, px, py, pz);
        bits[3] = dist_bits(x.w, y.w, z.w, px, py, pz);
#pragma unroll
        for (int i = 0; i < 4; ++i) {
            if ((bits[i] >> BSHIFT) <= T) {
                uint64_t key = ((uint64_t)bits[i] << 32) | (uint32_t)(n + i);
                uint32_t pos = atomicAdd(&lcnt, 1u);
                if (pos < LCAP) {
                    lbuf[pos] = key;
                } else {                       // pathological overflow fallback
                    uint32_t g = atomicAdd(gcnt, 1u);
                    if (g < CAP) cand[(size_t)b * CAP + g] = key;
                }
            }
        }
    }
    __syncthreads();
    uint32_t m = lcnt < LCAP ? lcnt : LCAP;
    if (threadIdx.x == 0) lbase = atomicAdd(gcnt, m);
    __syncthreads();
    uint32_t bb = lbase;
    for (uint32_t i = threadIdx.x; i < m; i += 256) {
        uint32_t g = bb + i;
        if (g < CAP) cand[(size_t)b * CAP + g] = lbuf[i];
    }
}

// Pass 4: per-batch bitonic sort (next-pow2 of candidate count) + output.
__global__ __launch_bounds__(1024) void sort_out_kernel(
        const float* __restrict__ pc,
        const uint32_t* __restrict__ cnt,
        const uint64_t* __restrict__ cand,
        float* __restrict__ out) {
    __shared__ uint64_t keys[CAP];
    int b = blockIdx.x;
    int tid = threadIdx.x;
    uint32_t m = cnt[b * CNT_STRIDE];
    if (m > CAP) m = CAP;
    int S = KSEL;                       // m >= KSEL always
    while (S < (int)m) S <<= 1;         // S in [1024, 4096]
    for (int i = tid; i < S; i += 1024)
        keys[i] = (i < (int)m) ? cand[(size_t)b * CAP + i] : 0xFFFFFFFFFFFFFFFFull;
    __syncthreads();
    for (int k = 2; k <= S; k <<= 1) {
        for (int j = k >> 1; j > 0; j >>= 1) {
            for (int i = tid; i < S; i += 1024) {
                int ixj = i ^ j;
                if (ixj > i) {
                    uint64_t a = keys[i];
                    uint64_t c = keys[ixj];
                    bool up = ((i & k) == 0);
                    if ((a > c) == up) { keys[i] = c; keys[ixj] = a; }
                }
            }
            __syncthreads();
        }
    }
    float* out_near = out;                             // (B,3,K)
    float* out_idx  = out + (size_t)BATCH * 3 * KSEL;  // (B,K)
    const float* base = pc + (size_t)b * 3 * NPTS;
    for (int kk = tid; kk < KSEL; kk += 1024) {
        uint64_t key = keys[kk];
        uint32_t idx = (uint32_t)key;
        out_idx[(size_t)b * KSEL + kk] = (float)idx;
        out_near[((size_t)b * 3 + 0) * KSEL + kk] = base[idx];
        out_near[((size_t)b * 3 + 1) * KSEL + kk] = base[NPTS + idx];
        out_near[((size_t)b * 3 + 2) * KSEL + kk] = base[2 * NPTS + idx];
    }
}

extern "C" void kernel_launch(void* const* d_in, const int* in_sizes, int n_in,
                              void* d_out, int out_size, void* d_ws, size_t ws_size,
                              hipStream_t stream) {
    const float* pc = (const float*)d_in[0];
    const float* P1 = (const float*)d_in[1];
    float* out = (float*)d_out;

    uint32_t* hist   = (uint32_t*)d_ws;
    uint32_t* thresh = (uint32_t*)((char*)d_ws + THRESH_OFF);
    uint32_t* cnt    = (uint32_t*)((char*)d_ws + CNT_OFF);
    uint64_t* cand   = (uint64_t*)((char*)d_ws + CAND_OFF);

    hipMemsetAsync(d_ws, 0, ZERO_BYTES, stream);

    hist_kernel<<<HBLK, 256, 0, stream>>>(pc, P1, hist);
    thresh_kernel<<<BATCH, 256, 0, stream>>>(hist, thresh);
    compact_kernel<<<CBLK, 256, 0, stream>>>(pc, P1, thresh, cnt, cand);
    sort_out_kernel<<<BATCH, 1024, 0, stream>>>(pc, cnt, cand, out);
}

// Round 4
// 82.175 us; speedup vs baseline: 14.1086x; 1.0081x over previous
//
#include <hip/hip_runtime.h>
#include <stdint.h>

#define BATCH 32
#define NPTS  262144
#define KSEL  1024
#define NBIN  8192          // 13-bit bins: sign+exp+4 mantissa
#define BSHIFT 19           // 32-13
#define CAP   4096
#define CNT_STRIDE 32       // pad per-batch counters to 128 B

#define HBLK  512           // histogram blocks (16 per batch)
#define PPB_H 16384         // points per hist block

#define CBLK  2048          // compact blocks (64 per batch)
#define PPB_C 4096          // points per compact block
#define LCAP  1024          // per-block LDS candidate buffer

// ws layout
#define HIST_BYTES   ((size_t)BATCH * NBIN * 4)          // 1 MiB
#define THRESH_OFF   (HIST_BYTES)                        // 128 B
#define CNT_OFF      (HIST_BYTES + 128)                  // 32*128 B
#define CAND_OFF     (HIST_BYTES + 128 + BATCH * CNT_STRIDE * 4)
#define ZERO_BYTES   (CAND_OFF)                          // ~1.05 MB

__device__ __forceinline__ uint32_t dist_bits(float x, float y, float z,
                                              float px, float py, float pz) {
#pragma clang fp contract(off)
    float dx = x - px;
    float dy = y - py;
    float dz = z - pz;
    float s = ((dx * dx) + (dy * dy)) + (dz * dz);
    return __float_as_uint(sqrtf(s));
}

// Pass 0: zero the {hist, thresh, cnt} region (runtime fillBuffer is 57 us;
// this is ~3 us).
__global__ __launch_bounds__(256) void zero_ws_kernel(uint4* __restrict__ p,
                                                      int n16) {
    int i = blockIdx.x * blockDim.x + threadIdx.x;
    if (i < n16) p[i] = uint4{0u, 0u, 0u, 0u};
}

// Pass 1: distance + LDS-privatized histogram of top-13 float bits.
__global__ __launch_bounds__(256) void hist_kernel(const float* __restrict__ pc,
                                                   const float* __restrict__ P1,
                                                   uint32_t* __restrict__ hist) {
    __shared__ uint32_t lh[NBIN];
    for (int i = threadIdx.x; i < NBIN; i += 256) lh[i] = 0;
    __syncthreads();

    const int b = blockIdx.x >> 4;          // 16 blocks per batch
    const int slice = blockIdx.x & 15;
    const float* base = pc + (size_t)b * 3 * NPTS;
    const int n0 = slice * PPB_H;
    const float px = P1[b * 3 + 0];
    const float py = P1[b * 3 + 1];
    const float pz = P1[b * 3 + 2];

#pragma unroll 4
    for (int it = 0; it < PPB_H / (256 * 4); ++it) {     // 16 iterations
        int n = n0 + ((it * 256 + threadIdx.x) << 2);
        float4 x = *(const float4*)(base + n);
        float4 y = *(const float4*)(base + NPTS + n);
        float4 z = *(const float4*)(base + 2 * NPTS + n);
        atomicAdd(&lh[dist_bits(x.x, y.x, z.x, px, py, pz) >> BSHIFT], 1u);
        atomicAdd(&lh[dist_bits(x.y, y.y, z.y, px, py, pz) >> BSHIFT], 1u);
        atomicAdd(&lh[dist_bits(x.z, y.z, z.z, px, py, pz) >> BSHIFT], 1u);
        atomicAdd(&lh[dist_bits(x.w, y.w, z.w, px, py, pz) >> BSHIFT], 1u);
    }
    __syncthreads();

    uint32_t* h = hist + (size_t)b * NBIN;
    for (int i = threadIdx.x; i < NBIN; i += 256) {
        uint32_t c = lh[i];
        if (c) atomicAdd(&h[i], c);
    }
}

// Pass 2: per-batch threshold bin T (bin containing the K-th smallest).
__global__ void thresh_kernel(const uint32_t* __restrict__ hist,
                              uint32_t* __restrict__ thresh) {
    int b = blockIdx.x;
    const uint32_t* h = hist + (size_t)b * NBIN;
    __shared__ uint32_t csum[256];
    int tid = threadIdx.x;                   // 256 threads × 32 bins each
    uint32_t s = 0;
    for (int i = 0; i < 32; ++i) s += h[tid * 32 + i];
    csum[tid] = s;
    __syncthreads();
    if (tid == 0) {
        uint32_t acc = 0;
        int chunk = 0;
        for (; chunk < 256; ++chunk) {
            if (acc + csum[chunk] >= (uint32_t)KSEL) break;
            acc += csum[chunk];
        }
        uint32_t t = chunk * 32;
        for (int i = 0; i < 32; ++i) {
            uint32_t c = h[chunk * 32 + i];
            if (acc + c >= (uint32_t)KSEL) { t = chunk * 32 + i; break; }
            acc += c;
        }
        thresh[b] = t;
    }
}

// Pass 3: compact candidates via LDS staging + one chunk-reservation atomic/block.
__global__ __launch_bounds__(256) void compact_kernel(
        const float* __restrict__ pc,
        const float* __restrict__ P1,
        const uint32_t* __restrict__ thresh,
        uint32_t* __restrict__ cnt,
        uint64_t* __restrict__ cand) {
    __shared__ uint64_t lbuf[LCAP];
    __shared__ uint32_t lcnt, lbase;
    if (threadIdx.x == 0) lcnt = 0;
    __syncthreads();

    const int b = blockIdx.x >> 6;          // 64 blocks per batch
    const int slice = blockIdx.x & 63;
    const float* base = pc + (size_t)b * 3 * NPTS;
    const int n0 = slice * PPB_C;
    const float px = P1[b * 3 + 0];
    const float py = P1[b * 3 + 1];
    const float pz = P1[b * 3 + 2];
    const uint32_t T = thresh[b];
    uint32_t* gcnt = &cnt[b * CNT_STRIDE];

#pragma unroll
    for (int it = 0; it < PPB_C / (256 * 4); ++it) {    // 4 iterations
        int n = n0 + ((it * 256 + threadIdx.x) << 2);
        float4 x = *(const float4*)(base + n);
        float4 y = *(const float4*)(base + NPTS + n);
        float4 z = *(const float4*)(base + 2 * NPTS + n);
        uint32_t bits[4];
        bits[0] = dist_bits(x.x, y.x, z.x, px, py, pz);
        bits[1] = dist_bits(x.y, y.y, z.y, px, py, pz);
        bits[2] = dist_bits(x.z, y.z, z.z, px, py, pz);
        bits[3] = dist_bits(x.w, y.w, z.w, px, py, pz);
#pragma unroll
        for (int i = 0; i < 4; ++i) {
            if ((bits[i] >> BSHIFT) <= T) {
                uint64_t key = ((uint64_t)bits[i] << 32) | (uint32_t)(n + i);
                uint32_t pos = atomicAdd(&lcnt, 1u);
                if (pos < LCAP) {
                    lbuf[pos] = key;
                } else {                       // pathological overflow fallback
                    uint32_t g = atomicAdd(gcnt, 1u);
                    if (g < CAP) cand[(size_t)b * CAP + g] = key;
                }
            }
        }
    }
    __syncthreads();
    uint32_t m = lcnt < LCAP ? lcnt : LCAP;
    if (threadIdx.x == 0) lbase = atomicAdd(gcnt, m);
    __syncthreads();
    uint32_t bb = lbase;
    for (uint32_t i = threadIdx.x; i < m; i += 256) {
        uint32_t g = bb + i;
        if (g < CAP) cand[(size_t)b * CAP + g] = lbuf[i];
    }
}

// Pass 4: per-batch bitonic sort (next-pow2 of candidate count) + output.
__global__ __launch_bounds__(1024) void sort_out_kernel(
        const float* __restrict__ pc,
        const uint32_t* __restrict__ cnt,
        const uint64_t* __restrict__ cand,
        float* __restrict__ out) {
    __shared__ uint64_t keys[CAP];
    int b = blockIdx.x;
    int tid = threadIdx.x;
    uint32_t m = cnt[b * CNT_STRIDE];
    if (m > CAP) m = CAP;
    int S = KSEL;                       // m >= KSEL always
    while (S < (int)m) S <<= 1;         // S in [1024, 4096]
    for (int i = tid; i < S; i += 1024)
        keys[i] = (i < (int)m) ? cand[(size_t)b * CAP + i] : 0xFFFFFFFFFFFFFFFFull;
    __syncthreads();
    for (int k = 2; k <= S; k <<= 1) {
        for (int j = k >> 1; j > 0; j >>= 1) {
            for (int i = tid; i < S; i += 1024) {
                int ixj = i ^ j;
                if (ixj > i) {
                    uint64_t a = keys[i];
                    uint64_t c = keys[ixj];
                    bool up = ((i & k) == 0);
                    if ((a > c) == up) { keys[i] = c; keys[ixj] = a; }
                }
            }
            __syncthreads();
        }
    }
    float* out_near = out;                             // (B,3,K)
    float* out_idx  = out + (size_t)BATCH * 3 * KSEL;  // (B,K)
    const float* base = pc + (size_t)b * 3 * NPTS;
    for (int kk = tid; kk < KSEL; kk += 1024) {
        uint64_t key = keys[kk];
        uint32_t idx = (uint32_t)key;
        out_idx[(size_t)b * KSEL + kk] = (float)idx;
        out_near[((size_t)b * 3 + 0) * KSEL + kk] = base[idx];
        out_near[((size_t)b * 3 + 1) * KSEL + kk] = base[NPTS + idx];
        out_near[((size_t)b * 3 + 2) * KSEL + kk] = base[2 * NPTS + idx];
    }
}

extern "C" void kernel_launch(void* const* d_in, const int* in_sizes, int n_in,
                              void* d_out, int out_size, void* d_ws, size_t ws_size,
                              hipStream_t stream) {
    const float* pc = (const float*)d_in[0];
    const float* P1 = (const float*)d_in[1];
    float* out = (float*)d_out;

    uint32_t* hist   = (uint32_t*)d_ws;
    uint32_t* thresh = (uint32_t*)((char*)d_ws + THRESH_OFF);
    uint32_t* cnt    = (uint32_t*)((char*)d_ws + CNT_OFF);
    uint64_t* cand   = (uint64_t*)((char*)d_ws + CAND_OFF);

    const int n16 = (int)(ZERO_BYTES / 16);
    zero_ws_kernel<<<(n16 + 255) / 256, 256, 0, stream>>>((uint4*)d_ws, n16);

    hist_kernel<<<HBLK, 256, 0, stream>>>(pc, P1, hist);
    thresh_kernel<<<BATCH, 256, 0, stream>>>(hist, thresh);
    compact_kernel<<<CBLK, 256, 0, stream>>>(pc, P1, thresh, cnt, cand);
    sort_out_kernel<<<BATCH, 1024, 0, stream>>>(pc, cnt, cand, out);
}